// Round 10
// baseline (214.749 us; speedup 1.0000x reference)
//
#include <hip/hip_runtime.h>
#include <hip/hip_bf16.h>
#include <stdint.h>

using bf16 = __hip_bfloat16;
typedef __attribute__((ext_vector_type(8))) short short8;
typedef __attribute__((ext_vector_type(4))) short short4b;
typedef __attribute__((ext_vector_type(4))) float f32x4;
typedef __attribute__((ext_vector_type(4))) unsigned int u32x4;

#if __has_builtin(__builtin_amdgcn_exp2f)
#define EXP2(x) __builtin_amdgcn_exp2f(x)
#else
#define EXP2(x) exp2f(x)
#endif

__device__ __forceinline__ short8 load8(const bf16* p) {
  return *reinterpret_cast<const short8*>(p);
}
__device__ __forceinline__ short f2b(float f) {
  return __builtin_bit_cast(short, __float2bfloat16(f));
}
__device__ __forceinline__ unsigned int pk2(float a, float b) {
  return (unsigned int)(unsigned short)f2b(a) |
         ((unsigned int)(unsigned short)f2b(b) << 16);
}
__device__ __forceinline__ void asy16(const bf16* g, bf16* l) {
  __builtin_amdgcn_global_load_lds(
      (const __attribute__((address_space(1))) void*)g,
      (__attribute__((address_space(3))) void*)l, 16, 0, 0);
}

// K fragment-order layout (per bh, per kt tile of 64 keys):
//   Kperm[((kc*2+half)*4+g)*128 + r*8 + j] = K[key=kc*16+r][d=half*32+8g+j]
// V fragment-order layout (PV contraction permuted by pi):
//   Vperm[((half*4+dvs)*4+g)*128 + r*8 + j] = V[dv=dvs*16+r][k=half*32+pi(g,j)]
//   pi(g,j) = (j>>2)*16 + 4g + (j&3)

// ---------------- fused prep kernel ----------------
__global__ void k_prep(const float4* __restrict__ x, ushort4* __restrict__ xb,
                       const float* __restrict__ Wq, const float* __restrict__ Wk,
                       const float* __restrict__ Wv, const float* __restrict__ Wo,
                       bf16* __restrict__ Wcat, bf16* __restrict__ Wot,
                       const int4* __restrict__ m4,
                       unsigned long long* __restrict__ bits) {
  int blk = blockIdx.x;
  const int tid = threadIdx.x;
  if (blk < 4096) {
    int i = blk * 256 + tid;
    float4 v = x[i];
    ushort4 o;
    o.x = (unsigned short)f2b(v.x);
    o.y = (unsigned short)f2b(v.y);
    o.z = (unsigned short)f2b(v.z);
    o.w = (unsigned short)f2b(v.w);
    xb[i] = o;
  } else if (blk < 4352) {
    int t = blk - 4096;
    __shared__ float T[64][65];
    if (t < 192) {
      int which = t >> 6;
      int h = (t >> 3) & 7, dt = t & 7;
      const float* W = (which == 0) ? Wq : ((which == 1) ? Wk : Wv);
#pragma unroll
      for (int p = 0; p < 4; ++p) {
        int row = p * 16 + (tid >> 4);
        float4 v = *(const float4*)(W + (size_t)(h * 512 + dt * 64 + row) * 64 +
                                    (tid & 15) * 4);
        T[row][(tid & 15) * 4 + 0] = v.x;
        T[row][(tid & 15) * 4 + 1] = v.y;
        T[row][(tid & 15) * 4 + 2] = v.z;
        T[row][(tid & 15) * 4 + 3] = v.w;
      }
      __syncthreads();
      float scale = (which == 0) ? 0.18033688011112042f : 1.0f;  // 0.125*log2e
      int jj = tid >> 2, i0 = (tid & 3) * 16;
#pragma unroll
      for (int q = 0; q < 2; ++q) {
        short8 o;
#pragma unroll
        for (int e = 0; e < 8; ++e) o[e] = f2b(T[i0 + q * 8 + e][jj] * scale);
        *(short8*)(Wcat + (size_t)(which * 512 + h * 64 + jj) * 512 + dt * 64 +
                   i0 + q * 8) = o;
      }
    } else {
      int t2 = t - 192;
      int h = t2 >> 3, et = t2 & 7;
#pragma unroll
      for (int p = 0; p < 4; ++p) {
        int row = p * 16 + (tid >> 4);
        float4 v = *(const float4*)(Wo + (size_t)(h * 64 + row) * 512 + et * 64 +
                                    (tid & 15) * 4);
        T[row][(tid & 15) * 4 + 0] = v.x;
        T[row][(tid & 15) * 4 + 1] = v.y;
        T[row][(tid & 15) * 4 + 2] = v.z;
        T[row][(tid & 15) * 4 + 3] = v.w;
      }
      __syncthreads();
      int jj = tid >> 2, i0 = (tid & 3) * 16;
#pragma unroll
      for (int q = 0; q < 2; ++q) {
        short8 o;
#pragma unroll
        for (int e = 0; e < 8; ++e) o[e] = f2b(T[i0 + q * 8 + e][jj]);
        *(short8*)(Wot + (size_t)(et * 64 + jj) * 512 + h * 64 + i0 + q * 8) = o;
      }
    }
  } else {
    int i = (blk - 4352) * 256 + tid;
    int4 v = m4[i];
    unsigned int nib = (unsigned)(v.x != 0) | ((unsigned)(v.y != 0) << 1) |
                       ((unsigned)(v.z != 0) << 2) | ((unsigned)(v.w != 0) << 3);
    unsigned long long w = (unsigned long long)nib << (4 * (tid & 15));
    w |= __shfl_xor(w, 1);
    w |= __shfl_xor(w, 2);
    w |= __shfl_xor(w, 4);
    w |= __shfl_xor(w, 8);
    if ((tid & 15) == 0) bits[i >> 4] = w;
  }
}

// ---------------- 128x128 GEMM core, BK=32 double-buffered ----------------
__device__ __forceinline__ void gemm128(const bf16* __restrict__ A,
                                        const bf16* __restrict__ Bt,
                                        bf16* As, bf16* Bs,
                                        int rowBase, int colBase,
                                        f32x4 acc[4][4]) {
  const int tid = threadIdx.x;
  const int lane = tid & 63, w = tid >> 6;
  const int g = lane >> 4, r = lane & 15;

  auto stage = [&](int buf, int s) {
#pragma unroll
    for (int p = 0; p < 2; ++p) {
      int c = p * 256 + tid;
      int row = c >> 2, gr = c & 3, sg = gr ^ (row & 3);
      asy16(A + (size_t)(rowBase + row) * 512 + s * 32 + sg * 8,
            As + buf * 4096 + c * 8);
    }
#pragma unroll
    for (int p = 0; p < 2; ++p) {
      int c = p * 256 + tid;
      int row = c >> 2, gr = c & 3, sg = gr ^ (row & 3);
      asy16(Bt + (size_t)(colBase + row) * 512 + s * 32 + sg * 8,
            Bs + buf * 4096 + c * 8);
    }
  };

  stage(0, 0);
  int buf = 0;
  const int rbl = (w >> 1) * 64, cbl = (w & 1) * 64;
  for (int s = 0; s < 16; ++s) {
    __syncthreads();
    if (s < 15) stage(buf ^ 1, s + 1);
    const bf16* a0 = As + buf * 4096;
    const bf16* b0 = Bs + buf * 4096;
    short8 af[4], bfr[4];
#pragma unroll
    for (int mt = 0; mt < 4; ++mt) {
      int row = rbl + mt * 16 + r;
      af[mt] = load8(a0 + (row * 4 + (g ^ (row & 3))) * 8);
    }
#pragma unroll
    for (int nt = 0; nt < 4; ++nt) {
      int col = cbl + nt * 16 + r;
      bfr[nt] = load8(b0 + (col * 4 + (g ^ (col & 3))) * 8);
    }
#pragma unroll
    for (int mt = 0; mt < 4; ++mt)
#pragma unroll
      for (int nt = 0; nt < 4; ++nt)
        acc[mt][nt] = __builtin_amdgcn_mfma_f32_16x16x32_bf16(
            af[mt], bfr[nt], acc[mt][nt], 0, 0, 0);
    buf ^= 1;
  }
}

// Fused QKV projection. Q -> [bh][n][64]; K -> Kperm; V -> Vperm.
__global__ __launch_bounds__(256, 3) void k_proj_qkv(
    const bf16* __restrict__ Xb, const bf16* __restrict__ Wcat,
    bf16* __restrict__ Qb, bf16* __restrict__ Kp, bf16* __restrict__ Vp) {
  __shared__ __align__(16) bf16 As[2 * 4096];
  __shared__ __align__(16) bf16 Bs[2 * 4096];
  int rowBase = blockIdx.x * 128, colBase = blockIdx.y * 128;
  f32x4 acc[4][4] = {};
  gemm128(Xb, Wcat, As, Bs, rowBase, colBase, acc);
  const int lane = threadIdx.x & 63, w = threadIdx.x >> 6;
  const int g = lane >> 4, r = lane & 15;
#pragma unroll
  for (int mt = 0; mt < 4; ++mt) {
    int row0 = rowBase + (w >> 1) * 64 + mt * 16 + 4 * g;
    int b = row0 >> 11, n0 = row0 & 2047;
    int kt = n0 >> 6;
#pragma unroll
    for (int nt = 0; nt < 4; ++nt) {
      int col = colBase + (w & 1) * 64 + nt * 16 + r;
      if (col < 512) {
        int hh = col >> 6, dk = col & 63;
        bf16* p0 = Qb + ((size_t)(b * 8 + hh) * 2048 + n0) * 64 + dk;
#pragma unroll
        for (int rr = 0; rr < 4; ++rr)
          p0[rr * 64] = __float2bfloat16(acc[mt][nt][rr]);
      } else if (col < 1024) {
        int hh = (col >> 6) & 7, dk = col & 63;
        int half = dk >> 5, gk = (dk >> 3) & 3, jj = dk & 7;
        int kr = n0 & 63;
        int kc = kr >> 4, r0 = kr & 15;
        bf16* base = Kp + (size_t)(b * 8 + hh) * 131072 + (size_t)kt * 4096 +
                     ((kc * 2 + half) * 4 + gk) * 128 + jj;
#pragma unroll
        for (int rr = 0; rr < 4; ++rr)
          base[(r0 + rr) * 8] = __float2bfloat16(acc[mt][nt][rr]);
      } else {
        int hdv = col - 1024;
        int hh = hdv >> 6, dv = hdv & 63;
        int dvs = dv >> 4, rv = dv & 15;
        int kcol0 = n0 & 63;
        int half = kcol0 >> 5, gv = (kcol0 >> 2) & 3;
        int j0 = ((kcol0 >> 4) & 1) * 4;
        short4b pkv;
#pragma unroll
        for (int rr = 0; rr < 4; ++rr) pkv[rr] = f2b(acc[mt][nt][rr]);
        *reinterpret_cast<short4b*>(
            Vp + (size_t)(b * 8 + hh) * 131072 + (size_t)kt * 4096 +
            (((half * 4 + dvs) * 4 + gv) * 16 + rv) * 8 + j0) = pkv;
      }
    }
  }
}

// Output projection
__global__ __launch_bounds__(256, 2) void k_proj_out(
    const bf16* __restrict__ O, const bf16* __restrict__ Wot,
    float* __restrict__ out) {
  __shared__ __align__(16) bf16 As[2 * 4096];
  __shared__ __align__(16) bf16 Bs[2 * 4096];
  int rowBase = blockIdx.x * 128, colBase = blockIdx.y * 128;
  f32x4 acc[4][4] = {};
  gemm128(O, Wot, As, Bs, rowBase, colBase, acc);
  const int lane = threadIdx.x & 63, w = threadIdx.x >> 6;
  const int g = lane >> 4, r = lane & 15;
#pragma unroll
  for (int mt = 0; mt < 4; ++mt) {
    int row0 = rowBase + (w >> 1) * 64 + mt * 16 + 4 * g;
#pragma unroll
    for (int nt = 0; nt < 4; ++nt) {
      int col = colBase + (w & 1) * 64 + nt * 16 + r;
#pragma unroll
      for (int rr = 0; rr < 4; ++rr)
        out[(size_t)(row0 + rr) * 512 + col] = acc[mt][nt][rr];
    }
  }
}

// ---------------- flash attention, split-K ----------------
// grid 1024 = (xcd-swizzled bh) x 16 qt-tiles x 2 k-halves; 256 thr = 4
// waves, 32 q-rows/wave. Each block handles 16 of the 32 kt tiles ->
// 4 blocks/CU (16 waves/CU) with per-block staging/LDS traffic UNCHANGED.
// Max-free exp2 softmax => partials combine by pure addition. Unnormalized
// O partial (bf16) -> P (=d_out scratch), l partial (f32) -> Lp.
__global__ __launch_bounds__(256, 4) void k_attn(const bf16* __restrict__ Q,
    const bf16* __restrict__ K, const bf16* __restrict__ V,
    const unsigned long long* __restrict__ MB,
    bf16* __restrict__ P, float* __restrict__ Lp) {
  const int blin = blockIdx.x;
  const int xcd = blin & 7;
  const int rest = blin >> 3;            // 0..127
  const int bh = xcd * 4 + (rest >> 5);
  const int sub = rest & 31;
  const int qt = sub >> 1;
  const int half = sub & 1;
  const int kt0 = half * 16;
  const int b = bh >> 3;
  const int tile = bh * 16 + qt;
  const int tid = threadIdx.x;
  const int lane = tid & 63;
  const int wave = tid >> 6;
  const int g = lane >> 4, r = lane & 15;
  const int qbase = qt * 128 + wave * 32;

  __shared__ __align__(16) bf16 Kl[2][4096];
  __shared__ __align__(16) bf16 Vl[2][4096];

  const bf16* Kp = K + (size_t)bh * 131072 + (size_t)kt0 * 4096;
  const bf16* Vp = V + (size_t)bh * 131072 + (size_t)kt0 * 4096;

  short8 qf[2][2];
#pragma unroll
  for (int s = 0; s < 2; ++s) {
    const bf16* Qp = Q + ((size_t)bh * 2048 + qbase + s * 16 + r) * 64;
    qf[s][0] = load8(Qp + g * 8);
    qf[s][1] = load8(Qp + 32 + g * 8);
  }
  const unsigned long long* Mp0 = MB + ((size_t)b * 2048 + qbase + r) * 32 + kt0;
  const unsigned long long* Mp1 =
      MB + ((size_t)b * 2048 + qbase + 16 + r) * 32 + kt0;

  short8 ones;
#pragma unroll
  for (int i = 0; i < 8; ++i) ones[i] = (short)0x3F80;  // bf16 1.0

  f32x4 acc[2][4] = {};
  f32x4 acc_l[2] = {};

  auto stage = [&](int buf, int ktl) {
    const bf16* Kg = Kp + (size_t)ktl * 4096;
    const bf16* Vg = Vp + (size_t)ktl * 4096;
#pragma unroll
    for (int p = 0; p < 2; ++p) {
      int c = p * 256 + tid;
      asy16(Kg + c * 8, &Kl[buf][0] + c * 8);
    }
#pragma unroll
    for (int p = 0; p < 2; ++p) {
      int c = p * 256 + tid;
      asy16(Vg + c * 8, &Vl[buf][0] + c * 8);
    }
  };

  stage(0, 0);
  int buf = 0;

  for (int ktl = 0; ktl < 16; ++ktl) {
    __syncthreads();
    if (ktl < 15) stage(buf ^ 1, ktl + 1);

    unsigned long long mw0 = Mp0[ktl];
    unsigned long long mw1 = Mp1[ktl];
    const bf16* kl = &Kl[buf][0];
    const bf16* vl = &Vl[buf][0];

    // S^T = K * Q^T (fragment-order K: contiguous b128 reads)
    f32x4 st[4][2];
#pragma unroll
    for (int kc = 0; kc < 4; ++kc) {
      short8 kf0 = load8(kl + ((kc * 2 + 0) * 4 + g) * 128 + r * 8);
      short8 kf1 = load8(kl + ((kc * 2 + 1) * 4 + g) * 128 + r * 8);
      f32x4 z0 = {};
      z0 = __builtin_amdgcn_mfma_f32_16x16x32_bf16(kf0, qf[0][0], z0, 0, 0, 0);
      st[kc][0] = __builtin_amdgcn_mfma_f32_16x16x32_bf16(kf1, qf[0][1], z0, 0, 0, 0);
      f32x4 z1 = {};
      z1 = __builtin_amdgcn_mfma_f32_16x16x32_bf16(kf0, qf[1][0], z1, 0, 0, 0);
      st[kc][1] = __builtin_amdgcn_mfma_f32_16x16x32_bf16(kf1, qf[1][1], z1, 0, 0, 0);
    }

    // max-free softmax
    short8 pa[2][2];
#pragma unroll
    for (int s = 0; s < 2; ++s) {
      unsigned long long mw = s ? mw1 : mw0;
      unsigned ml = (unsigned)mw >> (4 * g);
      unsigned mh = (unsigned)(mw >> 32) >> (4 * g);
      float p[16];
#pragma unroll
      for (int kc = 0; kc < 4; ++kc)
#pragma unroll
        for (int rr = 0; rr < 4; ++rr) {
          float e = EXP2(st[kc][s][rr]);
          unsigned wsel = (kc & 2) ? mh : ml;
          bool bad = (wsel >> (((kc & 1) << 4) + rr)) & 1u;
          p[kc * 4 + rr] = bad ? 0.f : e;
        }
      u32x4 q0, q1;
#pragma unroll
      for (int i2 = 0; i2 < 4; ++i2) {
        q0[i2] = pk2(p[2 * i2], p[2 * i2 + 1]);
        q1[i2] = pk2(p[8 + 2 * i2], p[8 + 2 * i2 + 1]);
      }
      pa[s][0] = __builtin_bit_cast(short8, q0);
      pa[s][1] = __builtin_bit_cast(short8, q1);
      acc_l[s] = __builtin_amdgcn_mfma_f32_16x16x32_bf16(pa[s][0], ones, acc_l[s], 0, 0, 0);
      acc_l[s] = __builtin_amdgcn_mfma_f32_16x16x32_bf16(pa[s][1], ones, acc_l[s], 0, 0, 0);
    }

    // PV (fragment-order V: direct b128 loads)
#pragma unroll
    for (int dvs = 0; dvs < 4; ++dvs) {
      short8 vb0 = load8(vl + ((0 * 4 + dvs) * 4 + g) * 128 + r * 8);
      short8 vb1 = load8(vl + ((1 * 4 + dvs) * 4 + g) * 128 + r * 8);
#pragma unroll
      for (int s = 0; s < 2; ++s) {
        acc[s][dvs] = __builtin_amdgcn_mfma_f32_16x16x32_bf16(pa[s][0], vb0, acc[s][dvs], 0, 0, 0);
        acc[s][dvs] = __builtin_amdgcn_mfma_f32_16x16x32_bf16(pa[s][1], vb1, acc[s][dvs], 0, 0, 0);
      }
    }
    buf ^= 1;
  }

  // epilogue: store unnormalized partials
  bf16* Pp = P + ((size_t)tile * 2 + half) * 8192;  // [qrow 128][dv 64]
#pragma unroll
  for (int s = 0; s < 2; ++s)
#pragma unroll
    for (int dvs = 0; dvs < 4; ++dvs)
#pragma unroll
      for (int rr = 0; rr < 4; ++rr)
        Pp[(wave * 32 + s * 16 + 4 * g + rr) * 64 + dvs * 16 + r] =
            __float2bfloat16(acc[s][dvs][rr]);
  if (r == 0) {
    float* Lq = Lp + ((size_t)tile * 2 + half) * 128 + wave * 32;
#pragma unroll
    for (int s = 0; s < 2; ++s)
      *reinterpret_cast<f32x4*>(Lq + s * 16 + 4 * g) = acc_l[s];
  }
}

// ---------------- split-K combine: Ob = (P0+P1) / (l0+l1) ----------------
__global__ __launch_bounds__(256) void k_combine(const bf16* __restrict__ P,
                                                 const float* __restrict__ Lp,
                                                 bf16* __restrict__ Ob) {
  int tile = blockIdx.x;  // 0..511
  int bh = tile >> 4, qt = tile & 15;
  int b = bh >> 3, h = bh & 7;
  int tid = threadIdx.x;
  __shared__ float inv[128];
  if (tid < 128) {
    float l = Lp[(size_t)(tile * 2 + 0) * 128 + tid] +
              Lp[(size_t)(tile * 2 + 1) * 128 + tid];
    inv[tid] = (l > 0.f) ? 1.f / l : 0.f;
  }
  __syncthreads();
  const bf16* P0 = P + (size_t)(tile * 2 + 0) * 8192;
  const bf16* P1 = P + (size_t)(tile * 2 + 1) * 8192;
#pragma unroll 4
  for (int it = 0; it < 32; ++it) {
    int idx = it * 256 + tid;
    int qrow = idx >> 6, dv = idx & 63;
    float v = __bfloat162float(P0[idx]) + __bfloat162float(P1[idx]);
    Ob[((size_t)b * 2048 + qt * 128 + qrow) * 512 + h * 64 + dv] =
        __float2bfloat16(v * inv[qrow]);
  }
}

// ---------------- launch ----------------

extern "C" void kernel_launch(void* const* d_in, const int* in_sizes, int n_in,
                              void* d_out, int out_size, void* d_ws, size_t ws_size,
                              hipStream_t stream) {
  const float* q    = (const float*)d_in[0];
  const int*   mask = (const int*)d_in[1];
  const float* Wq   = (const float*)d_in[2];
  const float* Wk   = (const float*)d_in[3];
  const float* Wv   = (const float*)d_in[4];
  const float* Wo   = (const float*)d_in[5];
  float* out = (float*)d_out;

  char* ws = (char*)d_ws;
  const size_t MB1 = 1024 * 1024;
  bf16* Xb   = (bf16*)(ws + 0);          // 8 MB [8192][512]
  bf16* Qb   = (bf16*)(ws + 8 * MB1);    // 8 MB [bh][n][64]
  bf16* Kpm  = (bf16*)(ws + 16 * MB1);   // 8 MB fragment-order K
  bf16* Vpm  = (bf16*)(ws + 24 * MB1);   // 8 MB fragment-order V
  bf16* Ob   = (bf16*)(ws + 32 * MB1);   // 8 MB [bn][512]
  unsigned long long* Mbits = (unsigned long long*)(ws + 40 * MB1);  // 2 MB
  bf16* Wcat = (bf16*)(ws + 42 * MB1);   // 1.5 MB
  bf16* Wot  = (bf16*)(ws + 42 * MB1 + 1536 * 512 * 2);  // 0.5 MB
  float* Lpart = (float*)(ws + 44 * MB1);  // 512 KB split-K l partials
  bf16* Ppart = (bf16*)d_out;  // 16 MB bf16 O partials (d_out reused as scratch)

  k_prep<<<20736, 256, 0, stream>>>((const float4*)q, (ushort4*)Xb,
                                    Wq, Wk, Wv, Wo, Wcat, Wot,
                                    (const int4*)mask, Mbits);
  k_proj_qkv<<<dim3(64, 12), 256, 0, stream>>>(Xb, Wcat, Qb, Kpm, Vpm);
  k_attn<<<1024, 256, 0, stream>>>(Qb, Kpm, Vpm, Mbits, Ppart, Lpart);
  k_combine<<<512, 256, 0, stream>>>(Ppart, Lpart, Ob);
  k_proj_out<<<dim3(64, 4), 256, 0, stream>>>(Ob, Wot, out);
}